// Round 2
// baseline (233.232 us; speedup 1.0000x reference)
//
#include <hip/hip_runtime.h>
#include <hip/hip_bf16.h>
#include <float.h>

#define N_NODES 100000
#define HID     512
#define NGRAPH  1024

typedef __bf16 bf16_t;
typedef bf16_t bf16x8 __attribute__((ext_vector_type(8)));
typedef float  f32x4  __attribute__((ext_vector_type(4)));

// XOR-swizzle for 64-byte LDS rows (BK=32 bf16): chunk ^= row&3.
__device__ __forceinline__ unsigned swz64(unsigned byteoff) {
    return byteoff ^ (((byteoff >> 6) & 3u) << 4);
}

// global -> LDS direct DMA, 16B per lane; LDS dest is wave-uniform base + lane*16.
#define GLOAD_LDS16(g, l)                                                        \
    __builtin_amdgcn_global_load_lds(                                            \
        (const __attribute__((address_space(1))) unsigned int*)(g),              \
        (__attribute__((address_space(3))) unsigned int*)(l), 16, 0, 0)

// ---------------- Kernel 0: W1 [K][N] f32 -> W1^T [N][K] bf16 ----------------
__global__ void __launch_bounds__(256) k_w1t(const float* __restrict__ w1,
                                             bf16_t* __restrict__ w1t) {
    int idx = blockIdx.x * 256 + threadIdx.x;   // 0 .. 262143
    int k = idx >> 9;
    int n = idx & 511;
    w1t[n * HID + k] = (bf16_t)w1[idx];
}

// ---------------- Kernel 1: fused GEMM + gelu + dot(W2) -> partial gates -----
// Block tile: 128 rows x 256 cols, BK=32, double-buffered LDS, 512 thr = 8 waves.
// A (f32 h): reg-stage issue-early / cvt+ds_write-late. B (bf16 w1t): global_load_lds
// with pre-swizzled global source (linear LDS dest). One barrier per K-iter.
__global__ void __launch_bounds__(512) k_gemm_gate(const float* __restrict__ h,
                                                   const bf16_t* __restrict__ w1t,
                                                   const float* __restrict__ b1,
                                                   const float* __restrict__ w2,
                                                   float* __restrict__ gpart) {
    __shared__ __align__(16) bf16_t As[2][128 * 32];   // 8 KB each, 64B rows
    __shared__ __align__(16) bf16_t Bs[2][256 * 32];   // 16 KB each, 64B rows
    __shared__ float gp[4][128];

    const int tid  = threadIdx.x;
    const int lane = tid & 63;
    const int wv   = tid >> 6;     // 0..7
    const int wm   = wv >> 2;      // 0..1  (M half)
    const int wn   = wv & 3;       // 0..3  (N quarter)
    const int l15  = lane & 15;
    const int l4   = lane >> 4;    // 0..3

    const int bidx = blockIdx.x;
    const int brow = (bidx >> 1) * 128;
    const int bcol = (bidx & 1) * 256;

    // ---- A staging geometry: thread -> (row, 8-elem chunk) ----
    const int  ar    = tid >> 2;                 // 0..127
    const int  ac    = tid & 3;                  // chunk (8 f32)
    const int  agrow = brow + ar;
    const bool aval  = agrow < N_NODES;
    const float* aptr = h + (size_t)agrow * HID + ac * 8;
    const unsigned a_lds_off = (unsigned)(ar * 64 + ((ac ^ (ar & 3)) * 16)); // swizzled dest

    // ---- B staging geometry: wave wv covers rows [wv*32, wv*32+32), 2 DMA instrs ----
    const int br0 = wv * 32 + (lane >> 2);       // rows for instr 0
    const int br1 = br0 + 16;                    // rows for instr 1
    const int bc  = lane & 3;
    const bf16_t* bptr0 = w1t + (size_t)(bcol + br0) * HID + ((bc ^ (br0 & 3)) * 8);
    const bf16_t* bptr1 = w1t + (size_t)(bcol + br1) * HID + ((bc ^ (br1 & 3)) * 8);

    f32x4 acc[4][4] = {};

    const int NT = 16;  // K tiles of 32

    // ---- prologue: stage tile 0 into buffer 0 ----
    {
        GLOAD_LDS16(bptr0, (char*)&Bs[0][0] + wv * 2048);
        GLOAD_LDS16(bptr1, (char*)&Bs[0][0] + wv * 2048 + 1024);
        float4 pa0 = make_float4(0.f, 0.f, 0.f, 0.f), pa1 = pa0;
        if (aval) {
            pa0 = reinterpret_cast<const float4*>(aptr)[0];
            pa1 = reinterpret_cast<const float4*>(aptr)[1];
        }
        bf16x8 v;
        v[0] = (bf16_t)pa0.x; v[1] = (bf16_t)pa0.y; v[2] = (bf16_t)pa0.z; v[3] = (bf16_t)pa0.w;
        v[4] = (bf16_t)pa1.x; v[5] = (bf16_t)pa1.y; v[6] = (bf16_t)pa1.z; v[7] = (bf16_t)pa1.w;
        *reinterpret_cast<bf16x8*>((char*)&As[0][0] + a_lds_off) = v;
        __syncthreads();   // compiler drains vmcnt (DMA) + lgkm before barrier
    }

    int cur = 0;
    for (int t = 0; t < NT; ++t) {
        const int  nxt = cur ^ 1;
        const bool pf  = (t + 1) < NT;

        // ---- issue-early: prefetch tile t+1 ----
        float4 pa0 = make_float4(0.f, 0.f, 0.f, 0.f), pa1 = pa0;
        if (pf) {
            if (aval) {
                const float* ap = aptr + (t + 1) * 32;
                pa0 = reinterpret_cast<const float4*>(ap)[0];
                pa1 = reinterpret_cast<const float4*>(ap)[1];
            }
            GLOAD_LDS16(bptr0 + (t + 1) * 32, (char*)&Bs[nxt][0] + wv * 2048);
            GLOAD_LDS16(bptr1 + (t + 1) * 32, (char*)&Bs[nxt][0] + wv * 2048 + 1024);
        }

        // ---- compute on buffer cur: 16 MFMA ----
        bf16x8 af[4], bfr[4];
        #pragma unroll
        for (int mf = 0; mf < 4; ++mf) {
            const int row = wm * 64 + mf * 16 + l15;
            af[mf] = *reinterpret_cast<const bf16x8*>(
                (const char*)&As[cur][0] + swz64(row * 64 + l4 * 16));
        }
        #pragma unroll
        for (int nf = 0; nf < 4; ++nf) {
            const int n = wn * 64 + nf * 16 + l15;
            bfr[nf] = *reinterpret_cast<const bf16x8*>(
                (const char*)&Bs[cur][0] + swz64(n * 64 + l4 * 16));
        }
        #pragma unroll
        for (int mf = 0; mf < 4; ++mf)
            #pragma unroll
            for (int nf = 0; nf < 4; ++nf)
                acc[mf][nf] = __builtin_amdgcn_mfma_f32_16x16x32_bf16(
                    af[mf], bfr[nf], acc[mf][nf], 0, 0, 0);

        // ---- write-late: cvt A prefetch and store into next buffer ----
        if (pf) {
            bf16x8 v;
            v[0] = (bf16_t)pa0.x; v[1] = (bf16_t)pa0.y; v[2] = (bf16_t)pa0.z; v[3] = (bf16_t)pa0.w;
            v[4] = (bf16_t)pa1.x; v[5] = (bf16_t)pa1.y; v[6] = (bf16_t)pa1.z; v[7] = (bf16_t)pa1.w;
            *reinterpret_cast<bf16x8*>((char*)&As[nxt][0] + a_lds_off) = v;
        }
        __syncthreads();
        cur = nxt;
    }

    // ---- epilogue: gelu(acc + b1) * w2, reduce over this block's 256 cols ----
    float pr[16];
    #pragma unroll
    for (int i = 0; i < 16; ++i) pr[i] = 0.f;
    #pragma unroll
    for (int nf = 0; nf < 4; ++nf) {
        const int cg    = bcol + wn * 64 + nf * 16 + l15;
        const float b1v = b1[cg];
        const float w2v = w2[cg];
        #pragma unroll
        for (int mf = 0; mf < 4; ++mf) {
            #pragma unroll
            for (int rr = 0; rr < 4; ++rr) {
                const float x  = acc[mf][nf][rr] + b1v;
                const float ge = 0.5f * x * (1.f + erff(x * 0.70710678118654752f));
                pr[mf * 4 + rr] = fmaf(ge, w2v, pr[mf * 4 + rr]);
            }
        }
    }
    // butterfly sum over the 16-lane column group (D cols live in lane&15)
    #pragma unroll
    for (int i = 0; i < 16; ++i) {
        float v = pr[i];
        v += __shfl_xor(v, 1);
        v += __shfl_xor(v, 2);
        v += __shfl_xor(v, 4);
        v += __shfl_xor(v, 8);
        pr[i] = v;
    }
    if (l15 == 0) {
        #pragma unroll
        for (int mf = 0; mf < 4; ++mf)
            #pragma unroll
            for (int rr = 0; rr < 4; ++rr)
                gp[wn][wm * 64 + mf * 16 + l4 * 4 + rr] = pr[mf * 4 + rr];
    }
    __syncthreads();
    if (tid < 128) {
        const int grow = brow + tid;
        if (grow < N_NODES) {
            gpart[(size_t)(bidx & 1) * N_NODES + grow] =
                gp[0][tid] + gp[1][tid] + gp[2][tid] + gp[3][tid];
        }
    }
}

// ---------------- Kernel 2: combine column-half partials + b2 ----------------
__global__ void __launch_bounds__(256) k_gate_reduce(const float* __restrict__ gpart,
                                                     const float* __restrict__ b2,
                                                     float* __restrict__ gate) {
    int i = blockIdx.x * 256 + threadIdx.x;
    if (i < N_NODES) gate[i] = gpart[i] + gpart[N_NODES + i] + b2[0];
}

// ---------------- Kernel 3: segment softmax + weighted pool ------------------
// One block (256 threads) per graph. batch_vec is sorted -> binary search bounds.
__global__ void __launch_bounds__(256) k_pool(const float* __restrict__ h,
                                              const int* __restrict__ bv,
                                              const float* __restrict__ gate,
                                              float* __restrict__ out) {
    const int g   = blockIdx.x;
    const int tid = threadIdx.x;
    __shared__ int   s_bounds[2];
    __shared__ float s_red[4];
    __shared__ float s_alpha[256];

    if (tid == 0) {
        int lo = 0, hi = N_NODES;
        while (lo < hi) { int mid = (lo + hi) >> 1; if (bv[mid] < g) lo = mid + 1; else hi = mid; }
        s_bounds[0] = lo;
        int lo2 = lo, hi2 = N_NODES;
        while (lo2 < hi2) { int mid = (lo2 + hi2) >> 1; if (bv[mid] < g + 1) lo2 = mid + 1; else hi2 = mid; }
        s_bounds[1] = lo2;
    }
    __syncthreads();
    const int start = s_bounds[0], end = s_bounds[1];

    float2 acc = make_float2(0.f, 0.f);
    if (start < end) {
        const int lane = tid & 63, wv = tid >> 6;
        // pass 1: segment max
        float lm = -FLT_MAX;
        for (int i = start + tid; i < end; i += 256) lm = fmaxf(lm, gate[i]);
        #pragma unroll
        for (int o = 32; o; o >>= 1) lm = fmaxf(lm, __shfl_xor(lm, o));
        if (lane == 0) s_red[wv] = lm;
        __syncthreads();
        const float m = fmaxf(fmaxf(s_red[0], s_red[1]), fmaxf(s_red[2], s_red[3]));
        __syncthreads();
        // pass 2: denom
        float ls = 0.f;
        for (int i = start + tid; i < end; i += 256) ls += expf(gate[i] - m);
        #pragma unroll
        for (int o = 32; o; o >>= 1) ls += __shfl_xor(ls, o);
        if (lane == 0) s_red[wv] = ls;
        __syncthreads();
        const float inv = 1.f / (s_red[0] + s_red[1] + s_red[2] + s_red[3]);
        // pass 3: chunked alpha-weighted sum of h rows; 2 cols per thread
        const float* hcol = h + tid * 2;
        for (int base = start; base < end; base += 256) {
            const int j = base + tid;
            const float av = (j < end) ? expf(gate[j] - m) * inv : 0.f;
            __syncthreads();
            s_alpha[tid] = av;
            __syncthreads();
            const int cnt = min(256, end - base);
            for (int jj = 0; jj < cnt; ++jj) {
                const float a = s_alpha[jj];
                const float2 hv = *reinterpret_cast<const float2*>(
                    hcol + (size_t)(base + jj) * HID);
                acc.x = fmaf(a, hv.x, acc.x);
                acc.y = fmaf(a, hv.y, acc.y);
            }
        }
    }
    *reinterpret_cast<float2*>(out + (size_t)g * HID + tid * 2) = acc;
}

// ---------------- launcher ---------------------------------------------------
extern "C" void kernel_launch(void* const* d_in, const int* in_sizes, int n_in,
                              void* d_out, int out_size, void* d_ws, size_t ws_size,
                              hipStream_t stream) {
    const float* h  = (const float*)d_in[0];
    const int*   bv = (const int*)d_in[1];
    const float* W1 = (const float*)d_in[2];
    const float* b1 = (const float*)d_in[3];
    const float* W2 = (const float*)d_in[4];
    const float* b2 = (const float*)d_in[5];
    float* out = (float*)d_out;

    char* ws = (char*)d_ws;
    bf16_t* w1t   = (bf16_t*)ws;                           // 512*512*2 = 524288 B
    float*  gpart = (float*)(ws + 524288);                 // 2*100000*4 = 800000 B
    float*  gate  = (float*)(ws + 524288 + 800000);        // 100000*4 B

    k_w1t<<<dim3(1024), dim3(256), 0, stream>>>(W1, w1t);
    k_gemm_gate<<<dim3(1564), dim3(512), 0, stream>>>(h, w1t, b1, W2, gpart);
    k_gate_reduce<<<dim3((N_NODES + 255) / 256), dim3(256), 0, stream>>>(gpart, b2, gate);
    k_pool<<<dim3(NGRAPH), dim3(256), 0, stream>>>(h, bv, gate, out);
}

// Round 3
// 200.321 us; speedup vs baseline: 1.1643x; 1.1643x over previous
//
#include <hip/hip_runtime.h>
#include <hip/hip_bf16.h>
#include <float.h>

#define N_NODES 100000
#define HID     512
#define NGRAPH  1024
#define BM      48            // rows per block
#define NBLK    ((N_NODES + BM - 1) / BM)   // 2084

typedef __bf16 bf16_t;
typedef bf16_t bf16x8 __attribute__((ext_vector_type(8)));
typedef float  f32x4  __attribute__((ext_vector_type(4)));

// global -> LDS direct DMA, 16B per lane; LDS dest is wave-uniform base + lane*16.
#define GLOAD_LDS16(g, l)                                                        \
    __builtin_amdgcn_global_load_lds(                                            \
        (const __attribute__((address_space(1))) unsigned int*)(g),              \
        (__attribute__((address_space(3))) unsigned int*)(l), 16, 0, 0)

// ---- Kernel 0: W1 [K][N] f32 -> tiled bf16 B: unit u=(kt*4+g)*512+col holds
// bf16x8 = W1[kt*32+g*8+e][col], e=0..7.  (16 kt) x (4 g) x (512 col) ----------
__global__ void __launch_bounds__(256) k_w1t_tiled(const float* __restrict__ w1,
                                                   bf16_t* __restrict__ bt) {
    const int u   = blockIdx.x * 256 + threadIdx.x;   // 0 .. 32767
    const int col = u & 511;
    const int g4  = u >> 9;          // kt*4 + g  (0..63)
    const int k0  = g4 * 8;          // kt*32 + g*8
    bf16x8 v;
    #pragma unroll
    for (int e = 0; e < 8; ++e)
        v[e] = (bf16_t)w1[(size_t)(k0 + e) * HID + col];
    *reinterpret_cast<bf16x8*>(bt + (size_t)u * 8) = v;
}

// ---- Kernel 1: fused GEMM + gelu + dot(W2) -> gate --------------------------
// Block: 48 rows x 512 cols x 512 K. A resident (48KB, swizzled), B streamed in
// 16 K-tiles of 32 (32KB, tiled layout, conflict-free). 512 thr = 8 waves, each
// wave owns 64 cols x all 48 rows: acc[3][4].
__global__ void __launch_bounds__(512, 4) k_gemm_gate(const float* __restrict__ h,
                                                      const bf16_t* __restrict__ bt,
                                                      const float* __restrict__ b1,
                                                      const float* __restrict__ w2,
                                                      const float* __restrict__ b2,
                                                      float* __restrict__ gate) {
    __shared__ __align__(16) char smem[BM * 1024 + 32768];   // 48KB A + 32KB B = 80KB
    bf16_t* As = (bf16_t*)smem;                   // [48 rows][512 k], 1KB rows, swizzled
    char*   Bs = smem + BM * 1024;                // [4 g][512 col] 16B units per K-tile

    const int tid  = threadIdx.x;
    const int lane = tid & 63;
    const int wv   = tid >> 6;     // 0..7 : wave owns cols [wv*64, wv*64+64)
    const int l15  = lane & 15;
    const int l4   = lane >> 4;    // 0..3

    const int brow = blockIdx.x * BM;

    // ================= stage A: 48 rows x 2KB, fully coalesced =================
    // unit idx = i*512 + tid : row = idx>>7, c16 = idx&127 (16B f32 chunk)
    f32x4 st[12];
    #pragma unroll
    for (int i = 0; i < 12; ++i) {
        const int idx = i * 512 + tid;
        const int row = idx >> 7;
        const int c16 = idx & 127;
        const int grow = brow + row;
        if (grow < N_NODES)
            st[i] = *reinterpret_cast<const f32x4*>(h + (size_t)grow * HID + c16 * 4);
        else
            st[i] = f32x4{0.f, 0.f, 0.f, 0.f};
    }
    // stage B tile 0 (DMA) while A loads are in flight
    {
        const char* src = (const char*)bt + (size_t)wv * 1024 + lane * 16;
        #pragma unroll
        for (int r = 0; r < 4; ++r)
            GLOAD_LDS16(src + r * 8192, Bs + r * 8192 + wv * 1024);
    }
    // cvt + swizzled LDS write of A
    #pragma unroll
    for (int i = 0; i < 12; ++i) {
        const int idx = i * 512 + tid;
        const int row = idx >> 7;
        const int c16 = idx & 127;
        const int chunk = c16 >> 1;                    // 16B bf16 chunk (k-span 8)
        const int half  = c16 & 1;
        short4 v;
        v.x = (short)(((unsigned short*)&st[i])[1] | 0);  // placeholder (replaced below)
        // proper cvt f32->bf16 (round-to-nearest via compiler cast)
        bf16_t b0 = (bf16_t)st[i][0], b1v_ = (bf16_t)st[i][1];
        bf16_t b2v_ = (bf16_t)st[i][2], b3 = (bf16_t)st[i][3];
        bf16_t tmp[4] = {b0, b1v_, b2v_, b3};
        *reinterpret_cast<double*>(
            (char*)As + row * 1024 + ((chunk ^ (row & 7)) * 16) + half * 8) =
            *reinterpret_cast<double*>(tmp);
    }
    __syncthreads();   // A in LDS + B[0] DMA drained

    // ================= K loop: 16 tiles of 32 ==================================
    f32x4 acc[3][4] = {};
    for (int kt = 0; kt < 16; ++kt) {
        // fragment loads from LDS
        bf16x8 af[3], bfr[4];
        #pragma unroll
        for (int mf = 0; mf < 3; ++mf) {
            const int row   = mf * 16 + l15;
            const int chunk = (kt * 4 + l4) ^ (row & 7);
            af[mf] = *reinterpret_cast<const bf16x8*>(
                (const char*)As + row * 1024 + chunk * 16);
        }
        #pragma unroll
        for (int nf = 0; nf < 4; ++nf) {
            const int col = wv * 64 + nf * 16 + l15;
            bfr[nf] = *reinterpret_cast<const bf16x8*>(
                Bs + (l4 * 512 + col) * 16);
        }
        __syncthreads();   // all frags read -> Bs reusable
        // issue next B tile DMA (lands under the MFMAs)
        if (kt < 15) {
            const char* src = (const char*)bt + (size_t)(kt + 1) * 32768
                              + (size_t)wv * 1024 + lane * 16;
            #pragma unroll
            for (int r = 0; r < 4; ++r)
                GLOAD_LDS16(src + r * 8192, Bs + r * 8192 + wv * 1024);
        }
        #pragma unroll
        for (int mf = 0; mf < 3; ++mf)
            #pragma unroll
            for (int nf = 0; nf < 4; ++nf)
                acc[mf][nf] = __builtin_amdgcn_mfma_f32_16x16x32_bf16(
                    af[mf], bfr[nf], acc[mf][nf], 0, 0, 0);
        __syncthreads();   // next B tile arrived (barrier drains vmcnt)
    }

    // ================= epilogue: gelu(acc+b1)*w2, reduce 512 cols ==============
    float pr[12];
    #pragma unroll
    for (int i = 0; i < 12; ++i) pr[i] = 0.f;
    #pragma unroll
    for (int nf = 0; nf < 4; ++nf) {
        const int cg    = wv * 64 + nf * 16 + l15;
        const float b1v = b1[cg];
        const float w2v = w2[cg];
        #pragma unroll
        for (int mf = 0; mf < 3; ++mf) {
            #pragma unroll
            for (int rr = 0; rr < 4; ++rr) {
                const float x  = acc[mf][nf][rr] + b1v;
                const float ge = 0.5f * x * (1.f + erff(x * 0.70710678118654752f));
                pr[mf * 4 + rr] = fmaf(ge, w2v, pr[mf * 4 + rr]);
            }
        }
    }
    #pragma unroll
    for (int i = 0; i < 12; ++i) {
        float v = pr[i];
        v += __shfl_xor(v, 1);
        v += __shfl_xor(v, 2);
        v += __shfl_xor(v, 4);
        v += __shfl_xor(v, 8);
        pr[i] = v;
    }
    // overlay per-wave row partials on Bs (all Bs reads are done)
    float* gp = (float*)Bs;      // [8 waves][48 rows]
    if (l15 == 0) {
        #pragma unroll
        for (int mf = 0; mf < 3; ++mf)
            #pragma unroll
            for (int rr = 0; rr < 4; ++rr)
                gp[wv * BM + mf * 16 + l4 * 4 + rr] = pr[mf * 4 + rr];
    }
    __syncthreads();
    if (tid < BM) {
        const int grow = brow + tid;
        if (grow < N_NODES) {
            float s = b2[0];
            #pragma unroll
            for (int w = 0; w < 8; ++w) s += gp[w * BM + tid];
            gate[grow] = s;
        }
    }
}

// ---- Kernel 2: segment softmax + weighted pool ------------------------------
__global__ void __launch_bounds__(256) k_pool(const float* __restrict__ h,
                                              const int* __restrict__ bv,
                                              const float* __restrict__ gate,
                                              float* __restrict__ out) {
    const int g   = blockIdx.x;
    const int tid = threadIdx.x;
    __shared__ int   s_bounds[2];
    __shared__ float s_red[4];
    __shared__ float s_alpha[256];

    if (tid == 0) {
        int lo = 0, hi = N_NODES;
        while (lo < hi) { int mid = (lo + hi) >> 1; if (bv[mid] < g) lo = mid + 1; else hi = mid; }
        s_bounds[0] = lo;
        int lo2 = lo, hi2 = N_NODES;
        while (lo2 < hi2) { int mid = (lo2 + hi2) >> 1; if (bv[mid] < g + 1) lo2 = mid + 1; else hi2 = mid; }
        s_bounds[1] = lo2;
    }
    __syncthreads();
    const int start = s_bounds[0], end = s_bounds[1];

    float2 acc = make_float2(0.f, 0.f);
    if (start < end) {
        const int lane = tid & 63, wv = tid >> 6;
        float lm = -FLT_MAX;
        for (int i = start + tid; i < end; i += 256) lm = fmaxf(lm, gate[i]);
        #pragma unroll
        for (int o = 32; o; o >>= 1) lm = fmaxf(lm, __shfl_xor(lm, o));
        if (lane == 0) s_red[wv] = lm;
        __syncthreads();
        const float m = fmaxf(fmaxf(s_red[0], s_red[1]), fmaxf(s_red[2], s_red[3]));
        __syncthreads();
        float ls = 0.f;
        for (int i = start + tid; i < end; i += 256) ls += expf(gate[i] - m);
        #pragma unroll
        for (int o = 32; o; o >>= 1) ls += __shfl_xor(ls, o);
        if (lane == 0) s_red[wv] = ls;
        __syncthreads();
        const float inv = 1.f / (s_red[0] + s_red[1] + s_red[2] + s_red[3]);
        const float* hcol = h + tid * 2;
        for (int base = start; base < end; base += 256) {
            const int j = base + tid;
            const float av = (j < end) ? expf(gate[j] - m) * inv : 0.f;
            __syncthreads();
            s_alpha[tid] = av;
            __syncthreads();
            const int cnt = min(256, end - base);
            for (int jj = 0; jj < cnt; ++jj) {
                const float a = s_alpha[jj];
                const float2 hv = *reinterpret_cast<const float2*>(
                    hcol + (size_t)(base + jj) * HID);
                acc.x = fmaf(a, hv.x, acc.x);
                acc.y = fmaf(a, hv.y, acc.y);
            }
        }
    }
    *reinterpret_cast<float2*>(out + (size_t)g * HID + tid * 2) = acc;
}

// ---- launcher ---------------------------------------------------------------
extern "C" void kernel_launch(void* const* d_in, const int* in_sizes, int n_in,
                              void* d_out, int out_size, void* d_ws, size_t ws_size,
                              hipStream_t stream) {
    const float* h  = (const float*)d_in[0];
    const int*   bv = (const int*)d_in[1];
    const float* W1 = (const float*)d_in[2];
    const float* b1 = (const float*)d_in[3];
    const float* W2 = (const float*)d_in[4];
    const float* b2 = (const float*)d_in[5];
    float* out = (float*)d_out;

    char* ws = (char*)d_ws;
    bf16_t* bt   = (bf16_t*)ws;                    // tiled B: 512*512*2 = 524288 B
    float*  gate = (float*)(ws + 524288);          // 100000*4 B

    k_w1t_tiled<<<dim3(128), dim3(256), 0, stream>>>(W1, bt);
    k_gemm_gate<<<dim3(NBLK), dim3(512), 0, stream>>>(h, bt, b1, W2, b2, gate);
    k_pool<<<dim3(NGRAPH), dim3(256), 0, stream>>>(h, bv, gate, out);
}